// Round 4
// baseline (295.385 us; speedup 1.0000x reference)
//
#include <hip/hip_runtime.h>

// Problem constants (GNNTimeModel): X[B,V,T], A[T,V,V], W[F,1] -> out[B,T,V*F]
#define BB 64
#define VV 64
#define TT 256
#define FF 64
constexpr float NEG_SLOPE = 0.01f;

// One block per (b,t). Stages sigmoid(A[t]) in LDS, does the V x V matvec
// against X[b,:,t], then expands with W and LeakyReLU, writing 16 KiB of
// contiguous float4 output per block. Pure HBM-write-bound by design.
__global__ __launch_bounds__(256) void gnn_fused(
    const float* __restrict__ X,
    const float* __restrict__ A,
    const float* __restrict__ W,
    float* __restrict__ out)
{
    __shared__ float adjS[VV][VV + 1];  // +1 pad: matvec column reads -> 2-way (free)
    __shared__ float xs[VV];
    __shared__ float hs[VV];

    const int tid = threadIdx.x;
    const int bid = blockIdx.x;
    const int t = bid / BB;   // consecutive blocks share A[t] (L2 locality)
    const int b = bid % BB;

    // --- stage adj_t = sigmoid(A[t]) with diagonal forced to 1 ---
    const float* At = A + (size_t)t * (VV * VV);
    #pragma unroll
    for (int i = 0; i < (VV * VV) / 256; ++i) {
        int idx = i * 256 + tid;
        int v = idx >> 6;
        int w = idx & 63;
        float a = At[idx];                       // coalesced 1 KiB/wave
        float s = 1.0f / (1.0f + __expf(-a));
        adjS[v][w] = (v == w) ? 1.0f : s;
    }

    // --- x[w] = X[b, w, t]  (stride-T reads, X is 4 MiB -> L2 resident) ---
    if (tid < VV) {
        xs[tid] = X[(size_t)b * (VV * TT) + (size_t)tid * TT + t];
    }
    __syncthreads();

    // --- matvec: H_agg[v] = sum_w adjS[v][w] * xs[w] ---
    {
        const int v = tid >> 2;       // 4 threads per output row
        const int part = tid & 3;     // each sums 16 w's
        float sum = 0.0f;
        #pragma unroll
        for (int i = 0; i < 16; ++i) {
            int w = part * 16 + i;
            sum += adjS[v][w] * xs[w];
        }
        sum += __shfl_xor(sum, 1);
        sum += __shfl_xor(sum, 2);
        if (part == 0) hs[v] = sum;
    }
    __syncthreads();

    // --- expansion: out[b,t,v,f] = leaky(hs[v] * W[f]), 4096 floats/block ---
    // Per-thread W fragment is loop-invariant: f0 = (4*idx4) & 63 = (4*tid) & 63.
    const float4 w4 = *reinterpret_cast<const float4*>(W + ((4 * tid) & 63));
    float4* out4 = reinterpret_cast<float4*>(
        out + (size_t)(b * TT + t) * (VV * FF));
    #pragma unroll
    for (int k = 0; k < 4; ++k) {
        int idx4 = k * 256 + tid;
        float h = hs[idx4 >> 4];   // 16 lanes share one element: LDS broadcast
        float4 r;
        r.x = h * w4.x;
        r.y = h * w4.y;
        r.z = h * w4.z;
        r.w = h * w4.w;
        r.x = (r.x >= 0.0f) ? r.x : NEG_SLOPE * r.x;
        r.y = (r.y >= 0.0f) ? r.y : NEG_SLOPE * r.y;
        r.z = (r.z >= 0.0f) ? r.z : NEG_SLOPE * r.z;
        r.w = (r.w >= 0.0f) ? r.w : NEG_SLOPE * r.w;
        out4[idx4] = r;
    }
}

extern "C" void kernel_launch(void* const* d_in, const int* in_sizes, int n_in,
                              void* d_out, int out_size, void* d_ws, size_t ws_size,
                              hipStream_t stream) {
    const float* X = (const float*)d_in[0];
    const float* A = (const float*)d_in[1];
    const float* W = (const float*)d_in[2];
    float* out = (float*)d_out;

    gnn_fused<<<BB * TT, 256, 0, stream>>>(X, A, W, out);
}